// Round 2
// baseline (423.729 us; speedup 1.0000x reference)
//
#include <hip/hip_runtime.h>
#include <hip/hip_bf16.h>

#define B_SZ   2
#define N_SEQ  2048
#define NH     16
#define DH     128
#define DM     2048
#define QBLK   64
#define KVBLK  32
#define NQT    (N_SEQ / QBLK)
#define MASK_VAL (-50000.0f)

typedef short bf16x8 __attribute__((ext_vector_type(8)));
typedef short bf16x4 __attribute__((ext_vector_type(4)));
typedef float f32x4  __attribute__((ext_vector_type(4)));

__device__ __forceinline__ short f2bf(float x) {
  unsigned u = __builtin_bit_cast(unsigned, x);
  unsigned r = (u + 0x7fffu + ((u >> 16) & 1u)) >> 16;
  return (short)r;
}

__device__ __forceinline__ int vswz(int d) {
  return (((d & 3) ^ ((d >> 2) & 3)) << 4);
}
__device__ __forceinline__ int pswz(int row) {
  return (((row & 3) ^ ((row >> 2) & 3)) << 4);
}

__global__ __launch_bounds__(256, 4)
void attn_fwd(const float* __restrict__ q, const float* __restrict__ k,
              const float* __restrict__ v, float* __restrict__ out) {
  __shared__ __align__(16) char lds[20480];
  char* ldsK  = lds;            // [32 rows][256 B] bf16 K-tile, XOR-swizzled
  char* ldsVT = lds + 8192;     // [128 rows][64 B] bf16 V^T-tile, swizzled
  char* ldsP  = lds + 16384;    // per-wave [16][64 B] P staging

  const int tid  = threadIdx.x;
  const int lane = tid & 63;
  const int w    = tid >> 6;
  const int g    = lane >> 4;
  const int lr   = lane & 15;

  const int bid = blockIdx.x;
  const int bh  = bid & 31;
  const int qt  = (NQT - 1) - (bid >> 5);   // heavy blocks first
  const int b   = bh >> 4;
  const int h   = bh & 15;
  const int q0  = qt * QBLK;
  const int wq0 = q0 + w * 16;

  const float scale = 0.08838834764831845f;  // 128^-0.5

  const float* kb = k + (size_t)b * N_SEQ * DM + h * DH;
  const float* vb = v + (size_t)b * N_SEQ * DM + h * DH;

  // ---- staging registers (reused across tiles; T14 async split)
  float4 kr[4];
  float  vr[16];
  const int d_   = tid & 127;
  const int jb0_ = tid >> 7;

  auto issue_loads = [&](int jt) {
    const float* kt = kb + (size_t)jt * DM;
    #pragma unroll
    for (int i = 0; i < 4; ++i) {
      int idx = i * 256 + tid;
      int row = idx >> 5;
      int c4  = idx & 31;
      kr[i] = *(const float4*)(kt + (size_t)row * DM + c4 * 4);
    }
    const float* vt = vb + (size_t)jt * DM;
    #pragma unroll
    for (int t2 = 0; t2 < 2; ++t2) {
      int jb = jb0_ + t2 * 2;
      #pragma unroll
      for (int jj = 0; jj < 8; ++jj)
        vr[t2 * 8 + jj] = vt[(size_t)(jb * 8 + jj) * DM + d_];
    }
  };

  auto write_lds = [&]() {
    #pragma unroll
    for (int i = 0; i < 4; ++i) {
      int idx = i * 256 + tid;
      int row = idx >> 5;
      int c4  = idx & 31;
      bf16x4 hv;
      hv[0] = f2bf(kr[i].x); hv[1] = f2bf(kr[i].y);
      hv[2] = f2bf(kr[i].z); hv[3] = f2bf(kr[i].w);
      *(bf16x4*)(ldsK + row * 256 + ((c4 * 8) ^ ((row & 7) << 4))) = hv;
    }
    #pragma unroll
    for (int t2 = 0; t2 < 2; ++t2) {
      int jb = jb0_ + t2 * 2;
      bf16x8 hv;
      #pragma unroll
      for (int jj = 0; jj < 8; ++jj) hv[jj] = f2bf(vr[t2 * 8 + jj]);
      *(bf16x8*)(ldsVT + d_ * 64 + ((jb * 16) ^ vswz(d_))) = hv;
    }
  };

  // ---- Q fragments (A-layout)
  bf16x8 qf[4];
  {
    const float* qbase = q + ((size_t)b * N_SEQ + (wq0 + lr)) * DM + h * DH + g * 8;
    #pragma unroll
    for (int s = 0; s < 4; ++s) {
      float4 a = *(const float4*)(qbase + s * 32);
      float4 c = *(const float4*)(qbase + s * 32 + 4);
      qf[s][0] = f2bf(a.x * scale); qf[s][1] = f2bf(a.y * scale);
      qf[s][2] = f2bf(a.z * scale); qf[s][3] = f2bf(a.w * scale);
      qf[s][4] = f2bf(c.x * scale); qf[s][5] = f2bf(c.y * scale);
      qf[s][6] = f2bf(c.z * scale); qf[s][7] = f2bf(c.w * scale);
    }
  }

  float m_[4], ll_[4];
  f32x4 o[8];
  #pragma unroll
  for (int r = 0; r < 4; ++r) { m_[r] = -INFINITY; ll_[r] = 0.f; }
  #pragma unroll
  for (int dt = 0; dt < 8; ++dt) o[dt] = (f32x4){0.f, 0.f, 0.f, 0.f};

  const int nt = (q0 + QBLK) / KVBLK;
  issue_loads(0);

  for (int t = 0; t < nt; ++t) {
    const int jt = t * KVBLK;
    if (t) __syncthreads();      // all waves done reading previous tile
    write_lds();                 // vmcnt-waits on in-flight loads, converts
    __syncthreads();
    if (t + 1 < nt) issue_loads(jt + KVBLK);   // overlap next loads w/ compute

    if (jt > wq0 + 15) continue;   // fully masked for this wave

    // ---- S = (Q*scale) K^T
    f32x4 s0 = {0,0,0,0}, s1 = {0,0,0,0};
    #pragma unroll
    for (int s = 0; s < 4; ++s) {
      bf16x8 k0 = *(const bf16x8*)(ldsK + lr * 256 +
                    ((s * 64 + g * 16) ^ ((lr & 7) << 4)));
      bf16x8 k1 = *(const bf16x8*)(ldsK + (16 + lr) * 256 +
                    ((s * 64 + g * 16) ^ ((lr & 7) << 4)));
      s0 = __builtin_amdgcn_mfma_f32_16x16x32_bf16(qf[s], k0, s0, 0, 0, 0);
      s1 = __builtin_amdgcn_mfma_f32_16x16x32_bf16(qf[s], k1, s1, 0, 0, 0);
    }

    // ---- causal mask
    if (jt + KVBLK > wq0 + 1) {
      #pragma unroll
      for (int r = 0; r < 4; ++r) {
        int irow = wq0 + g * 4 + r;
        s0[r] = (jt + lr      > irow) ? MASK_VAL : s0[r];
        s1[r] = (jt + 16 + lr > irow) ? MASK_VAL : s1[r];
      }
    }

    // ---- online softmax
    float tm[4];
    #pragma unroll
    for (int r = 0; r < 4; ++r) tm[r] = fmaxf(s0[r], s1[r]);
    #pragma unroll
    for (int off = 1; off < 16; off <<= 1) {
      #pragma unroll
      for (int r = 0; r < 4; ++r) tm[r] = fmaxf(tm[r], __shfl_xor(tm[r], off));
    }
    float alpha[4];
    #pragma unroll
    for (int r = 0; r < 4; ++r) {
      float mn = fmaxf(m_[r], tm[r]);
      alpha[r] = __expf(m_[r] - mn);
      m_[r] = mn;
      s0[r] = __expf(s0[r] - mn);
      s1[r] = __expf(s1[r] - mn);
    }
    float ts[4];
    #pragma unroll
    for (int r = 0; r < 4; ++r) ts[r] = s0[r] + s1[r];
    #pragma unroll
    for (int off = 1; off < 16; off <<= 1) {
      #pragma unroll
      for (int r = 0; r < 4; ++r) ts[r] += __shfl_xor(ts[r], off);
    }
    #pragma unroll
    for (int r = 0; r < 4; ++r) ll_[r] = ll_[r] * alpha[r] + ts[r];
    #pragma unroll
    for (int dt = 0; dt < 8; ++dt) {
      #pragma unroll
      for (int r = 0; r < 4; ++r) o[dt][r] *= alpha[r];
    }

    // ---- P -> bf16 LDS -> A-fragment (per-wave buffer, in-wave round trip)
    char* myP = ldsP + (w << 10);
    #pragma unroll
    for (int r = 0; r < 4; ++r) {
      int prow = g * 4 + r;
      int sw   = pswz(prow);
      *(short*)(myP + prow * 64 + ((lr * 2)        ^ sw)) = f2bf(s0[r]);
      *(short*)(myP + prow * 64 + (((16 + lr) * 2) ^ sw)) = f2bf(s1[r]);
    }
    bf16x8 pa = *(const bf16x8*)(myP + lr * 64 + ((g * 16) ^ pswz(lr)));

    // ---- O += P V
    #pragma unroll
    for (int dt = 0; dt < 8; ++dt) {
      int drow = dt * 16 + lr;
      bf16x8 vv = *(const bf16x8*)(ldsVT + drow * 64 + ((g * 16) ^ vswz(drow)));
      o[dt] = __builtin_amdgcn_mfma_f32_16x16x32_bf16(pa, vv, o[dt], 0, 0, 0);
    }
  }

  // ---- epilogue
  float inv[4];
  #pragma unroll
  for (int r = 0; r < 4; ++r) inv[r] = 1.0f / ll_[r];
  float* ob = out + ((size_t)b * N_SEQ + wq0) * DM + h * DH;
  #pragma unroll
  for (int dt = 0; dt < 8; ++dt) {
    #pragma unroll
    for (int r = 0; r < 4; ++r)
      ob[(size_t)(g * 4 + r) * DM + dt * 16 + lr] = o[dt][r] * inv[r];
  }
}

extern "C" void kernel_launch(void* const* d_in, const int* in_sizes, int n_in,
                              void* d_out, int out_size, void* d_ws, size_t ws_size,
                              hipStream_t stream) {
  const float* q = (const float*)d_in[0];
  const float* k = (const float*)d_in[1];
  const float* v = (const float*)d_in[2];
  float* out = (float*)d_out;
  dim3 grid(B_SZ * NH * NQT);
  attn_fwd<<<grid, 256, 0, stream>>>(q, k, v, out);
}

// Round 3
// 110.547 us; speedup vs baseline: 3.8330x; 3.8330x over previous
//
#include <hip/hip_runtime.h>
#include <hip/hip_bf16.h>

#define B_SZ   2
#define N_SEQ  2048
#define NH     16
#define DH     128
#define DM     2048
#define QB     128               // 4 warps x 32 q-rows
#define KVB    64
#define NQT    (N_SEQ / QB)      // 16
#define MASK_VAL (-50000.0f)

typedef short bf16x8 __attribute__((ext_vector_type(8)));
typedef short bf16x4 __attribute__((ext_vector_type(4)));
typedef float f32x4  __attribute__((ext_vector_type(4)));
typedef float f32x16 __attribute__((ext_vector_type(16)));
typedef unsigned u32;
typedef unsigned u32x4 __attribute__((ext_vector_type(4)));

__device__ __forceinline__ short f2bf(float x) {
  unsigned u = __builtin_bit_cast(unsigned, x);
  return (short)((u + 0x7fffu + ((u >> 16) & 1u)) >> 16);
}
__device__ __forceinline__ u32 pk2(float a, float b) {
  return (u32)(unsigned short)f2bf(a) | ((u32)(unsigned short)f2bf(b) << 16);
}

__global__ __launch_bounds__(256, 2)
void attn_fwd(const float* __restrict__ q, const float* __restrict__ k,
              const float* __restrict__ v, float* __restrict__ out) {
  __shared__ __align__(16) char  ldsK[64 * 256];     // K[64][128] bf16, XOR-swizzled rows
  __shared__ __align__(16) char  ldsVT[128 * 128];   // VT[128 d][64 j] bf16, swizzled
  __shared__ __align__(16) float ldsA[4 * 32];       // per-warp alpha/inv broadcast

  const int tid  = threadIdx.x;
  const int lane = tid & 63;
  const int w    = tid >> 6;
  const int h    = lane >> 5;     // wave half
  const int il   = lane & 31;     // q-row slot / d-col slot

  const int bid = blockIdx.x;
  const int bh  = bid & 31;
  // paired mapping: CU pairs (bid, bid+256) get qt and 15-qt -> constant work
  const int qt  = (bid < 256) ? (bid >> 5) : (NQT - 1 - ((bid - 256) >> 5));
  const int b   = bh >> 4;
  const int hd  = bh & 15;
  const int q0  = qt * QB;
  const int wq0 = q0 + w * 32;
  const int irow = wq0 + il;

  const float scale = 0.08838834764831845f;  // 128^-0.5

  const float* kb = k + (size_t)b * N_SEQ * DM + hd * DH;
  const float* vb = v + (size_t)b * N_SEQ * DM + hd * DH;

  // ---- Q fragments (B-operand of swapped QK): qf[s][jj] = Q[irow][16s+8h+jj]*scale
  bf16x8 qf[8];
  {
    const float* qr = q + ((size_t)b * N_SEQ + irow) * DM + hd * DH + h * 8;
    #pragma unroll
    for (int s = 0; s < 8; ++s) {
      float4 a = *(const float4*)(qr + s * 16);
      float4 c = *(const float4*)(qr + s * 16 + 4);
      qf[s][0] = f2bf(a.x * scale); qf[s][1] = f2bf(a.y * scale);
      qf[s][2] = f2bf(a.z * scale); qf[s][3] = f2bf(a.w * scale);
      qf[s][4] = f2bf(c.x * scale); qf[s][5] = f2bf(c.y * scale);
      qf[s][6] = f2bf(c.z * scale); qf[s][7] = f2bf(c.w * scale);
    }
  }

  float m_ = -INFINITY, ll = 0.f;
  f32x16 o[4];
  #pragma unroll
  for (int dt = 0; dt < 4; ++dt)
    #pragma unroll
    for (int r = 0; r < 16; ++r) o[dt][r] = 0.f;

  const int kswz = (il & 7) << 4;   // row swizzle for both ldsK reads and VT reads
  const int d_   = tid & 127;       // VT staging: this thread's d-column
  const int jh   = tid >> 7;

  const int nt = 2 * qt + 2;
  for (int t = 0; t < nt; ++t) {
    const int jt = t * KVB;
    if (t) __syncthreads();

    // ---- stage K tile [jt..jt+64) x 128 -> bf16 LDS (row-major, swizzled)
    {
      const float* kt = kb + (size_t)jt * DM;
      #pragma unroll
      for (int i = 0; i < 8; ++i) {
        int idx = i * 256 + tid;
        int row = idx >> 5;          // 0..63
        int c4  = idx & 31;
        float4 f = *(const float4*)(kt + (size_t)row * DM + c4 * 4);
        bf16x4 hv;
        hv[0] = f2bf(f.x); hv[1] = f2bf(f.y); hv[2] = f2bf(f.z); hv[3] = f2bf(f.w);
        *(bf16x4*)(ldsK + row * 256 + ((c4 * 8) ^ ((row & 7) << 4))) = hv;
      }
    }
    // ---- stage V^T: VT[d][j], column-coalesced global reads
    {
      const float* vt = vb + (size_t)jt * DM;
      #pragma unroll
      for (int t2 = 0; t2 < 4; ++t2) {
        int j0 = jh * 32 + t2 * 8;
        bf16x8 hv;
        #pragma unroll
        for (int jj = 0; jj < 8; ++jj)
          hv[jj] = f2bf(vt[(size_t)(j0 + jj) * DM + d_]);
        *(bf16x8*)(ldsVT + d_ * 128 + ((j0 * 2) ^ ((d_ & 7) << 4))) = hv;
      }
    }
    __syncthreads();

    if (jt > wq0 + 31) continue;           // fully masked for this warp
    const bool act1 = (jt + 32 <= wq0 + 31);

    // ---- S^T = K Q^T : two 32x32 j-tiles over K-dim 128
    f32x16 sc0 = {0,0,0,0,0,0,0,0,0,0,0,0,0,0,0,0};
    f32x16 sc1 = {0,0,0,0,0,0,0,0,0,0,0,0,0,0,0,0};
    #pragma unroll
    for (int s = 0; s < 8; ++s) {
      bf16x8 kf0 = *(const bf16x8*)(ldsK + il * 256 + ((s * 32 + h * 16) ^ kswz));
      sc0 = __builtin_amdgcn_mfma_f32_32x32x16_bf16(kf0, qf[s], sc0, 0, 0, 0);
    }
    if (act1) {
      #pragma unroll
      for (int s = 0; s < 8; ++s) {
        bf16x8 kf1 = *(const bf16x8*)(ldsK + (32 + il) * 256 + ((s * 32 + h * 16) ^ kswz));
        sc1 = __builtin_amdgcn_mfma_f32_32x32x16_bf16(kf1, qf[s], sc1, 0, 0, 0);
      }
    }

    // ---- causal mask (lane owns q-row irow; reg r holds j = jt + jtile*32 + (r&3)+8*(r>>2)+4h)
    if (jt + 31 > wq0) {
      #pragma unroll
      for (int r = 0; r < 16; ++r) {
        int j = jt + (r & 3) + 8 * (r >> 2) + 4 * h;
        sc0[r] = (j > irow) ? MASK_VAL : sc0[r];
      }
    }
    if (act1 && (jt + 63 > wq0)) {
      #pragma unroll
      for (int r = 0; r < 16; ++r) {
        int j = jt + 32 + (r & 3) + 8 * (r >> 2) + 4 * h;
        sc1[r] = (j > irow) ? MASK_VAL : sc1[r];
      }
    }

    // ---- in-register online softmax (one shfl for the half-exchange)
    float pmax = sc0[0];
    #pragma unroll
    for (int r = 1; r < 16; ++r) pmax = fmaxf(pmax, sc0[r]);
    if (act1) {
      #pragma unroll
      for (int r = 0; r < 16; ++r) pmax = fmaxf(pmax, sc1[r]);
    }
    pmax = fmaxf(pmax, __shfl_xor(pmax, 32));
    const float mnew = fmaxf(m_, pmax);

    #pragma unroll
    for (int r = 0; r < 16; ++r) sc0[r] = __expf(sc0[r] - mnew);
    if (act1) {
      #pragma unroll
      for (int r = 0; r < 16; ++r) sc1[r] = __expf(sc1[r] - mnew);
    }
    float rs = 0.f;
    #pragma unroll
    for (int r = 0; r < 16; ++r) rs += sc0[r];
    if (act1) {
      #pragma unroll
      for (int r = 0; r < 16; ++r) rs += sc1[r];
    }
    rs += __shfl_xor(rs, 32);

    const float alpha = __expf(m_ - mnew);
    ll = ll * alpha + rs;
    const bool changed = mnew > m_;
    m_ = mnew;

    if (__any(changed)) {
      ldsA[w * 32 + il] = alpha;           // both halves write same value (benign)
      f32x4 av[4];
      #pragma unroll
      for (int m = 0; m < 4; ++m)
        av[m] = *(const f32x4*)(ldsA + w * 32 + 8 * m + 4 * h);
      #pragma unroll
      for (int dt = 0; dt < 4; ++dt)
        #pragma unroll
        for (int m = 0; m < 4; ++m)
          #pragma unroll
          for (int r2 = 0; r2 < 4; ++r2)
            o[dt][m * 4 + r2] *= av[m][r2];
    }

    // ---- pack P -> bf16 A-fragments via pair-pack + permlane32_swap (T12)
    bf16x8 pa0[2], pa1[2];
    {
      #pragma unroll
      for (int ss = 0; ss < 2; ++ss) {
        u32 w0 = pk2(sc0[8 * ss + 0], sc0[8 * ss + 1]);
        u32 w1 = pk2(sc0[8 * ss + 2], sc0[8 * ss + 3]);
        u32 w2 = pk2(sc0[8 * ss + 4], sc0[8 * ss + 5]);
        u32 w3 = pk2(sc0[8 * ss + 6], sc0[8 * ss + 7]);
        asm volatile("v_permlane32_swap_b32 %0, %1" : "+v"(w0), "+v"(w2));
        asm volatile("v_permlane32_swap_b32 %0, %1" : "+v"(w1), "+v"(w3));
        u32x4 t4 = {w0, w1, w2, w3};
        pa0[ss] = __builtin_bit_cast(bf16x8, t4);
      }
    }
    if (act1) {
      #pragma unroll
      for (int ss = 0; ss < 2; ++ss) {
        u32 w0 = pk2(sc1[8 * ss + 0], sc1[8 * ss + 1]);
        u32 w1 = pk2(sc1[8 * ss + 2], sc1[8 * ss + 3]);
        u32 w2 = pk2(sc1[8 * ss + 4], sc1[8 * ss + 5]);
        u32 w3 = pk2(sc1[8 * ss + 6], sc1[8 * ss + 7]);
        asm volatile("v_permlane32_swap_b32 %0, %1" : "+v"(w0), "+v"(w2));
        asm volatile("v_permlane32_swap_b32 %0, %1" : "+v"(w1), "+v"(w3));
        u32x4 t4 = {w0, w1, w2, w3};
        pa1[ss] = __builtin_bit_cast(bf16x8, t4);
      }
    }

    // ---- O += P V   (B-frag: contiguous b128 from swizzled VT rows)
    #pragma unroll
    for (int dt = 0; dt < 4; ++dt) {
      const int drow = dt * 32 + il;          // drow&7 == il&7 -> kswz
      char* vrow = ldsVT + drow * 128;
      {
        bf16x8 vf0 = *(const bf16x8*)(vrow + ((0 * 32 + 16 * h) ^ kswz));
        o[dt] = __builtin_amdgcn_mfma_f32_32x32x16_bf16(pa0[0], vf0, o[dt], 0, 0, 0);
        bf16x8 vf1 = *(const bf16x8*)(vrow + ((1 * 32 + 16 * h) ^ kswz));
        o[dt] = __builtin_amdgcn_mfma_f32_32x32x16_bf16(pa0[1], vf1, o[dt], 0, 0, 0);
      }
      if (act1) {
        bf16x8 vf2 = *(const bf16x8*)(vrow + ((2 * 32 + 16 * h) ^ kswz));
        o[dt] = __builtin_amdgcn_mfma_f32_32x32x16_bf16(pa1[0], vf2, o[dt], 0, 0, 0);
        bf16x8 vf3 = *(const bf16x8*)(vrow + ((3 * 32 + 16 * h) ^ kswz));
        o[dt] = __builtin_amdgcn_mfma_f32_32x32x16_bf16(pa1[1], vf3, o[dt], 0, 0, 0);
      }
    }
  }

  // ---- epilogue: distribute 1/ll to D-layout rows, normalize, store
  ldsA[w * 32 + il] = 1.0f / ll;
  f32x4 iv[4];
  #pragma unroll
  for (int m = 0; m < 4; ++m)
    iv[m] = *(const f32x4*)(ldsA + w * 32 + 8 * m + 4 * h);

  float* ob = out + ((size_t)b * N_SEQ + wq0) * DM + hd * DH;
  #pragma unroll
  for (int dt = 0; dt < 4; ++dt) {
    #pragma unroll
    for (int m = 0; m < 4; ++m) {
      #pragma unroll
      for (int r2 = 0; r2 < 4; ++r2) {
        int i_loc = 8 * m + 4 * h + r2;      // C/D row
        ob[(size_t)i_loc * DM + dt * 32 + il] = o[dt][m * 4 + r2] * iv[m][r2];
      }
    }
  }
}

extern "C" void kernel_launch(void* const* d_in, const int* in_sizes, int n_in,
                              void* d_out, int out_size, void* d_ws, size_t ws_size,
                              hipStream_t stream) {
  const float* q = (const float*)d_in[0];
  const float* k = (const float*)d_in[1];
  const float* v = (const float*)d_in[2];
  float* out = (float*)d_out;
  dim3 grid(B_SZ * NH * NQT);   // 512 blocks, 2 per CU
  attn_fwd<<<grid, 256, 0, stream>>>(q, k, v, out);
}